// Round 9
// baseline (285.014 us; speedup 1.0000x reference)
//
#include <hip/hip_runtime.h>

#define K_CODES 1024
#define DIM 64
#define B_ 16
#define T_ 8192
#define N_ (B_*T_)          // 131072 vectors
#define EPSF 1e-5f
#define SMARGIN 5e-4f       // score-space margin >= 3x practical mfma error bound

typedef __attribute__((ext_vector_type(8))) short short8;   // 8 bf16 = 4 VGPR
typedef __attribute__((ext_vector_type(4))) float f32x4;

__device__ __forceinline__ unsigned bf16_rne(float f) {
    unsigned u = __float_as_uint(f);
    return (u + 0x7fffu + ((u >> 16) & 1u)) >> 16;
}

// ---- prep: e -> bf16 hi/lo tables, fp64 table, half-norms fp64 + fp32 ----
__global__ __launch_bounds__(64) void vq_prep(const float* __restrict__ emb,
                                              double* __restrict__ e64,
                                              double* __restrict__ snh64,
                                              float* __restrict__ snh32,
                                              unsigned short* __restrict__ ehib,
                                              unsigned short* __restrict__ elob) {
    const int k = blockIdx.x;
    const int d = threadIdx.x;
    const float ef = emb[k * DIM + d];
    const unsigned rh = bf16_rne(ef);
    const float hif = __uint_as_float(rh << 16);
    const float lof = ef - hif;                   // exact (Sterbenz)
    const unsigned rl = bf16_rne(lof);
    ehib[k * DIM + d] = (unsigned short)rh;
    elob[k * DIM + d] = (unsigned short)rl;

    const double ed = (double)ef;
    e64[k * DIM + d] = ed;
    double s = ed * ed;
    #pragma unroll
    for (int off = 32; off; off >>= 1) s += __shfl_down(s, off, 64);
    if (d == 0) { snh64[k] = 0.5 * s; snh32[k] = (float)(0.5 * s); }
}

// ---- transpose x[b][d][t] -> xT[b*T+t][d] for the coalesced code-reduce ----
__global__ __launch_bounds__(256) void vq_xt(const float* __restrict__ x,
                                             float* __restrict__ xT) {
    __shared__ float tile[64][65];
    const int bb = blockIdx.x >> 7;           // batch
    const int t0 = (blockIdx.x & 127) << 6;   // 64-t tile
    const int tr = threadIdx.x & 63;
    const int dr = threadIdx.x >> 6;          // 4 rows per pass
    const float* xp = x + ((size_t)bb << 19) + t0;
    #pragma unroll
    for (int i = 0; i < 16; i++) {
        const int d = i * 4 + dr;
        tile[d][tr] = xp[((size_t)d << 13) + tr];
    }
    __syncthreads();
    float* op = xT + (((size_t)bb << 13) + t0) * 64;
    #pragma unroll
    for (int i = 0; i < 16; i++) {
        const int t = i * 4 + dr;
        op[(size_t)t * 64 + tr] = tile[tr][t];
    }
}

// ---- screen: split-bf16 MFMA scores, per-lane top-2, k-split x2 ----
// block = 4 waves = 2 vector-groups x 2 code-halves; 64 vectors/block; grid 2048.
// NOTE: no min-waves clamp — round 8's (256,8) forced VGPR=32 and spilled.
__global__ __launch_bounds__(256) void vq_screen(const float* __restrict__ x,
                                                 const unsigned short* __restrict__ ehib,
                                                 const unsigned short* __restrict__ elob,
                                                 const float* __restrict__ snh32,
                                                 const float* __restrict__ emb,
                                                 float* __restrict__ out,
                                                 int* __restrict__ idx32,
                                                 int* __restrict__ flagcnt,
                                                 int* __restrict__ flagids) {
    __shared__ float red[64][4];         // khalf=1 results: b1, b2, idx-bits
    __shared__ int sidx[64];             // merged: code index, or -1 = flagged

    const int tid   = threadIdx.x;
    const int wid   = tid >> 6;
    const int lane  = tid & 63;
    const int vgrp  = wid & 1;           // which 32-vector group
    const int khalf = wid >> 1;          // codes 0-511 or 512-1023
    const int ln15  = lane & 15;
    const int lhi   = lane >> 4;         // 0..3

    const int blk  = blockIdx.x;                 // 2048 blocks x 64 vectors
    const int b    = blk >> 7;                   // 128 blocks per batch row
    const int tblk = (blk & 127) << 6;           // 64-vector tile base t
    const int t0   = tblk + vgrp * 32;           // wave's 32 vectors
    const float* xb = x + ((size_t)b << 19);

    // frag[nt][s]: lane holds B[k = s*32 + lhi*8 + j, n = ln15] = x[d=k][t0+nt*16+ln15]
    short8 xbh[2][2], xbl[2][2];
    #pragma unroll
    for (int nt = 0; nt < 2; nt++) {
        const int t = t0 + nt * 16 + ln15;
        #pragma unroll
        for (int s = 0; s < 2; s++) {
            #pragma unroll
            for (int j = 0; j < 8; j++) {
                const int d = s * 32 + lhi * 8 + j;
                const float xf = xb[((size_t)d << 13) + t];
                const unsigned rh = bf16_rne(xf);
                const float hif = __uint_as_float(rh << 16);
                const unsigned rl = bf16_rne(xf - hif);
                xbh[nt][s][j] = (short)rh;
                xbl[nt][s][j] = (short)rl;
            }
        }
    }

    float b1[2] = {-1e30f, -1e30f}, b2[2] = {-1e30f, -1e30f};
    int   bi[2] = {0, 0};

    const int kbase = khalf << 9;        // this wave's 512 codes
    for (int kt = 0; kt < 32; kt++) {
        const int k0 = kbase + (kt << 4);
        const size_t arow = ((size_t)(k0 + ln15) << 6) + lhi * 8;
        const short8 ah0 = *(const short8*)(ehib + arow);
        const short8 ah1 = *(const short8*)(ehib + arow + 32);
        const short8 al0 = *(const short8*)(elob + arow);
        const short8 al1 = *(const short8*)(elob + arow + 32);
        const f32x4 snq = *(const f32x4*)(snh32 + k0 + lhi * 4);

        #pragma unroll
        for (int nt = 0; nt < 2; nt++) {
            f32x4 acc = {0.f, 0.f, 0.f, 0.f};
            acc = __builtin_amdgcn_mfma_f32_16x16x32_bf16(ah0, xbh[nt][0], acc, 0, 0, 0);
            acc = __builtin_amdgcn_mfma_f32_16x16x32_bf16(ah1, xbh[nt][1], acc, 0, 0, 0);
            acc = __builtin_amdgcn_mfma_f32_16x16x32_bf16(ah0, xbl[nt][0], acc, 0, 0, 0);
            acc = __builtin_amdgcn_mfma_f32_16x16x32_bf16(ah1, xbl[nt][1], acc, 0, 0, 0);
            acc = __builtin_amdgcn_mfma_f32_16x16x32_bf16(al0, xbh[nt][0], acc, 0, 0, 0);
            acc = __builtin_amdgcn_mfma_f32_16x16x32_bf16(al1, xbh[nt][1], acc, 0, 0, 0);
            // C/D: col = ln15 (vector), row = lhi*4 + r (code) [m89-verified]
            #pragma unroll
            for (int r = 0; r < 4; r++) {
                const float m = acc[r] - snq[r];
                b2[nt] = fmaxf(b2[nt], fminf(b1[nt], m));
                if (m > b1[nt]) { b1[nt] = m; bi[nt] = k0 + lhi * 4 + r; }
            }
        }
    }

    // ---- merge top-2 across the 4 lane-groups holding each column ----
    #pragma unroll
    for (int nt = 0; nt < 2; nt++) {
        float B1 = b1[nt], B2 = b2[nt]; int I = bi[nt];
        #pragma unroll
        for (int off = 16; off <= 32; off <<= 1) {
            const float o1 = __shfl_xor(B1, off, 64);
            const float o2 = __shfl_xor(B2, off, 64);
            const int   oi = __shfl_xor(I,  off, 64);
            const float nb2 = fmaxf(fminf(B1, o1), fmaxf(B2, o2));
            if (o1 > B1 || (o1 == B1 && oi < I)) { B1 = o1; I = oi; }
            B2 = nb2;
        }
        // ---- cross-wave (k-split) merge through LDS ----
        if (khalf == 1 && lane < 16) {
            const int vloc = vgrp * 32 + nt * 16 + lane;
            red[vloc][0] = B1; red[vloc][1] = B2; red[vloc][2] = __int_as_float(I);
        }
        b1[nt] = B1; b2[nt] = B2; bi[nt] = I;
    }
    __syncthreads();

    if (khalf == 0) {
        #pragma unroll
        for (int nt = 0; nt < 2; nt++) {
            if (lane < 16) {
                const int vloc = vgrp * 32 + nt * 16 + lane;
                const float ob1 = red[vloc][0];
                const float ob2 = red[vloc][1];
                const int   oi  = __float_as_int(red[vloc][2]);
                float B1 = b1[nt], B2 = b2[nt]; int I = bi[nt];
                if (ob1 > B1) { B2 = fmaxf(B1, ob2); B1 = ob1; I = oi; }  // kh0 idx < kh1 idx
                else          { B2 = fmaxf(B2, ob1); }
                sidx[vloc] = (B1 - B2 <= SMARGIN) ? -1 : I;
            }
        }
    }
    __syncthreads();

    // ---- epilogue: thread = (vector vloc, dim quarter qd); NO fp32 atomics ----
    const int vloc = tid & 63;
    const int qd   = tid >> 6;           // 16-dim quarter
    const int t    = tblk + vloc;
    const int I    = sidx[vloc];
    const int v    = (b << 13) + t;

    if (I < 0) {
        if (qd == 0) { const int p = atomicAdd(flagcnt, 1); flagids[p] = v; }
    } else {
        if (qd == 0) idx32[v] = I;
        const float* eq = emb + I * DIM + qd * 16;
        #pragma unroll
        for (int j = 0; j < 16; j++) {
            const int d = qd * 16 + j;
            const float xf = xb[((size_t)d << 13) + t];
            out[((size_t)b << 19) + ((size_t)d << 13) + t] = xf + (eq[j] - xf);
        }
    }
}

// ---------------- rescan: one block per flagged vector, exact fp64 ----------
__global__ __launch_bounds__(256) void vq_rescan(const float* __restrict__ x,
                                                 const float* __restrict__ emb,
                                                 const double* __restrict__ e64,
                                                 const double* __restrict__ snh64,
                                                 float* __restrict__ out,
                                                 int* __restrict__ idx32,
                                                 const int* __restrict__ flagcnt,
                                                 const int* __restrict__ flagids) {
    __shared__ double sb[256];
    __shared__ int    si[256];
    const int tid   = threadIdx.x;
    const int cslot = tid >> 2;          // 0..63 code slot (block-wide)
    const int dg    = tid & 3;           // 16-dim group
    const int count = *flagcnt;

    for (int i = blockIdx.x; i < count; i += gridDim.x) {
        const int v = flagids[i];
        const int b = v >> 13, t = v & (T_ - 1);
        const float* xb = x + ((size_t)b << 19) + t;

        double xd[16];
        #pragma unroll
        for (int j = 0; j < 16; j++) xd[j] = (double)xb[(size_t)(dg * 16 + j) << 13];

        double best = -1e300; int bi_ = 0;
        for (int cc = 0; cc < 16; cc++) {
            const int k = cc * 64 + cslot;
            const double* ek = e64 + (size_t)k * DIM + dg * 16;
            double a = 0.0;
            #pragma unroll
            for (int j = 0; j < 16; j++) a = __fma_rn(xd[j], ek[j], a);
            a += __shfl_xor(a, 1, 64);
            a += __shfl_xor(a, 2, 64);   // full dot across 4 dim-groups
            const double m = a - snh64[k];
            if (m > best) { best = m; bi_ = k; }  // ascending k: first-max kept
        }

        __syncthreads();                 // protect sb/si from previous iteration
        sb[tid] = best; si[tid] = bi_;
        __syncthreads();
        for (int s = 128; s > 0; s >>= 1) {
            if (tid < s) {
                const double ob = sb[tid + s]; const int oi = si[tid + s];
                if (ob > sb[tid] || (ob == sb[tid] && oi < si[tid])) {
                    sb[tid] = ob; si[tid] = oi;
                }
            }
            __syncthreads();
        }
        const int I = si[0];

        if (tid < 64) {                  // epilogue: thread = dim
            const float xf = xb[(size_t)tid << 13];
            out[((size_t)b << 19) + ((size_t)tid << 13) + t] = xf + (emb[I * DIM + tid] - xf);
            if (tid == 0) idx32[v] = I;
        }
    }
}

// ---- hist: per-block LDS histogram of idx32 -> global counts ----
__global__ __launch_bounds__(1024) void vq_hist(const int* __restrict__ idx32,
                                                int* __restrict__ counts) {
    __shared__ int h[K_CODES];
    const int tid = threadIdx.x;
    h[tid] = 0;
    __syncthreads();
    const int base = blockIdx.x * 2048 + tid;
    atomicAdd(&h[idx32[base]], 1);
    atomicAdd(&h[idx32[base + 1024]], 1);
    __syncthreads();
    const int c = h[tid];
    if (c) atomicAdd(&counts[tid], c);
}

// ---- scan: exclusive prefix sum of counts -> offsets, cursors ----
__global__ __launch_bounds__(1024) void vq_scan(const int* __restrict__ counts,
                                                int* __restrict__ offsets,
                                                int* __restrict__ cursors) {
    __shared__ int s[K_CODES];
    const int tid = threadIdx.x;
    const int c0 = counts[tid];
    int incl = c0;
    s[tid] = incl;
    __syncthreads();
    for (int off = 1; off < K_CODES; off <<= 1) {
        const int add = (tid >= off) ? s[tid - off] : 0;
        __syncthreads();
        incl += add;
        s[tid] = incl;
        __syncthreads();
    }
    const int excl = incl - c0;
    offsets[tid] = excl;
    cursors[tid] = excl;
}

// ---- scatter: counting-sort vector ids by code ----
__global__ __launch_bounds__(256) void vq_scatter(const int* __restrict__ idx32,
                                                  int* __restrict__ cursors,
                                                  int* __restrict__ order) {
    const int v = blockIdx.x * 256 + threadIdx.x;
    const int k = idx32[v];
    const int p = atomicAdd(&cursors[k], 1);
    order[p] = v;
}

// ---- reduce: block per code; sum assigned x, divide by cluster_size ----
__global__ __launch_bounds__(64) void vq_reduce(const float* __restrict__ x,
                                                const float* __restrict__ xT,
                                                const int* __restrict__ order,
                                                const int* __restrict__ offsets,
                                                const int* __restrict__ counts,
                                                float* __restrict__ newemb,
                                                int use_xt) {
    __shared__ int lv[2048];
    const int k = blockIdx.x;
    const int d = threadIdx.x;
    const int off = offsets[k];
    const int cnt = counts[k];
    float sum = 0.f;
    for (int base = 0; base < cnt; base += 2048) {
        const int m = min(2048, cnt - base);
        __syncthreads();
        for (int i = d; i < m; i += 64) lv[i] = order[off + base + i];
        __syncthreads();
        if (use_xt) {
            for (int i = 0; i < m; i++) sum += xT[(size_t)lv[i] * 64 + d];
        } else {
            for (int i = 0; i < m; i++) {
                const int v = lv[i];
                sum += x[((size_t)(v >> 13) << 19) + ((size_t)d << 13) + (v & (T_ - 1))];
            }
        }
    }
    const float c = (float)cnt;
    const float cluster = (c + EPSF) / (131072.0f + 1024.0f * EPSF) * 131072.0f;
    newemb[k * DIM + d] = sum / cluster;
}

extern "C" void kernel_launch(void* const* d_in, const int* in_sizes, int n_in,
                              void* d_out, int out_size, void* d_ws, size_t ws_size,
                              hipStream_t stream) {
    const float* x   = (const float*)d_in[0];
    const float* emb = (const float*)d_in[1];

    char* ws = (char*)d_ws;
    double*         e64     = (double*)(ws);                  //  524288 B
    double*         snh64   = (double*)(ws + 524288);         //    8192 B
    float*          snh32   = (float*)(ws + 532480);          //    4096 B
    unsigned short* ehib    = (unsigned short*)(ws + 536576); //  131072 B
    unsigned short* elob    = (unsigned short*)(ws + 667648); //  131072 B
    int*            idx32   = (int*)(ws + 798720);            //  524288 B
    int*            order   = (int*)(ws + 1323008);           //  524288 B
    int*            counts  = (int*)(ws + 1847296);           //    4096 B
    int*            flagcnt = (int*)(ws + 1851392);           //      64 B
    int*            offsets = (int*)(ws + 1851456);           //    4096 B
    int*            cursors = (int*)(ws + 1855552);           //    4096 B
    int*            flagids = (int*)(ws + 1859648);           //  524288 B
    float*          xT      = (float*)(ws + 2383936);         // 33554432 B (optional)
    const int use_xt = (ws_size >= (size_t)2383936 + 33554432) ? 1 : 0;

    float* out    = (float*)d_out;
    float* newemb = out + (size_t)B_ * DIM * T_;

    // zero counts + flagcnt (contiguous) every launch
    hipMemsetAsync(counts, 0, 4096 + 64, stream);

    vq_prep<<<K_CODES, 64, 0, stream>>>(emb, e64, snh64, snh32, ehib, elob);
    if (use_xt) vq_xt<<<2048, 256, 0, stream>>>(x, xT);
    vq_screen<<<N_ / 64, 256, 0, stream>>>(x, ehib, elob, snh32, emb, out, idx32,
                                           flagcnt, flagids);
    vq_rescan<<<512, 256, 0, stream>>>(x, emb, e64, snh64, out, idx32,
                                       flagcnt, flagids);
    vq_hist<<<N_ / 2048, 1024, 0, stream>>>(idx32, counts);
    vq_scan<<<1, 1024, 0, stream>>>(counts, offsets, cursors);
    vq_scatter<<<N_ / 256, 256, 0, stream>>>(idx32, cursors, order);
    vq_reduce<<<K_CODES, 64, 0, stream>>>(x, xT, order, offsets, counts, newemb, use_xt);
}

// Round 10
// 229.174 us; speedup vs baseline: 1.2437x; 1.2437x over previous
//
#include <hip/hip_runtime.h>

#define K_CODES 1024
#define DIM 64
#define B_ 16
#define T_ 8192
#define N_ (B_*T_)          // 131072 vectors
#define EPSF 1e-5f
#define SMARGIN 5e-4f       // score-space margin >= 3x practical mfma error bound

typedef __attribute__((ext_vector_type(8))) short short8;   // 8 bf16 = 4 VGPR
typedef __attribute__((ext_vector_type(4))) float f32x4;

__device__ __forceinline__ unsigned bf16_rne(float f) {
    unsigned u = __float_as_uint(f);
    return (u + 0x7fffu + ((u >> 16) & 1u)) >> 16;
}

// ---- prep: e -> bf16 hi/lo tables, fp64 table, half-norms fp64 + fp32 ----
__global__ __launch_bounds__(64) void vq_prep(const float* __restrict__ emb,
                                              double* __restrict__ e64,
                                              double* __restrict__ snh64,
                                              float* __restrict__ snh32,
                                              unsigned short* __restrict__ ehib,
                                              unsigned short* __restrict__ elob) {
    const int k = blockIdx.x;
    const int d = threadIdx.x;
    const float ef = emb[k * DIM + d];
    const unsigned rh = bf16_rne(ef);
    const float hif = __uint_as_float(rh << 16);
    const float lof = ef - hif;                   // exact (Sterbenz)
    const unsigned rl = bf16_rne(lof);
    ehib[k * DIM + d] = (unsigned short)rh;
    elob[k * DIM + d] = (unsigned short)rl;

    const double ed = (double)ef;
    e64[k * DIM + d] = ed;
    double s = ed * ed;
    #pragma unroll
    for (int off = 32; off; off >>= 1) s += __shfl_down(s, off, 64);
    if (d == 0) { snh64[k] = 0.5 * s; snh32[k] = (float)(0.5 * s); }
}

// ---- transpose x[b][d][t] -> xT[b*T+t][d] for the coalesced code-reduce ----
__global__ __launch_bounds__(256) void vq_xt(const float* __restrict__ x,
                                             float* __restrict__ xT) {
    __shared__ float tile[64][65];
    const int bb = blockIdx.x >> 7;           // batch
    const int t0 = (blockIdx.x & 127) << 6;   // 64-t tile
    const int tr = threadIdx.x & 63;
    const int dr = threadIdx.x >> 6;          // 4 rows per pass
    const float* xp = x + ((size_t)bb << 19) + t0;
    #pragma unroll
    for (int i = 0; i < 16; i++) {
        const int d = i * 4 + dr;
        tile[d][tr] = xp[((size_t)d << 13) + tr];
    }
    __syncthreads();
    float* op = xT + (((size_t)bb << 13) + t0) * 64;
    #pragma unroll
    for (int i = 0; i < 16; i++) {
        const int t = i * 4 + dr;
        op[(size_t)t * 64 + tr] = tile[tr][t];
    }
}

// ---- screen: split-bf16 MFMA, 64 vec/wave (nt=4), prefetch-pipelined ----
// block = 4 waves = 2 vector-groups(64) x 2 code-halves; 128 vec/block; grid 1024.
__global__ __launch_bounds__(256) void vq_screen(const float* __restrict__ x,
                                                 const unsigned short* __restrict__ ehib,
                                                 const unsigned short* __restrict__ elob,
                                                 const float* __restrict__ snh32,
                                                 const float* __restrict__ emb,
                                                 float* __restrict__ out,
                                                 int* __restrict__ idx32,
                                                 int* __restrict__ flagcnt,
                                                 int* __restrict__ flagids) {
    __shared__ float red[128][4];        // khalf=1 results: b1, b2, idx-bits
    __shared__ int sidx[128];            // merged: code index, or -1 = flagged

    const int tid   = threadIdx.x;
    const int wid   = tid >> 6;
    const int lane  = tid & 63;
    const int vgrp  = wid & 1;           // which 64-vector group
    const int khalf = wid >> 1;          // codes 0-511 or 512-1023
    const int ln15  = lane & 15;
    const int lhi   = lane >> 4;         // 0..3

    const int blk  = blockIdx.x;                 // 1024 blocks x 128 vectors
    const int b    = blk >> 6;                   // 64 blocks per batch row
    const int tblk = (blk & 63) << 7;            // 128-vector tile base t
    const int t0   = tblk + vgrp * 64;           // wave's 64 vectors
    const float* xb = x + ((size_t)b << 19);

    // frag[nt][s]: lane holds B[k = s*32 + lhi*8 + j, n = ln15] = x[d=k][t0+nt*16+ln15]
    short8 xbh[4][2], xbl[4][2];
    #pragma unroll
    for (int nt = 0; nt < 4; nt++) {
        const int t = t0 + nt * 16 + ln15;
        #pragma unroll
        for (int s = 0; s < 2; s++) {
            #pragma unroll
            for (int j = 0; j < 8; j++) {
                const int d = s * 32 + lhi * 8 + j;
                const float xf = xb[((size_t)d << 13) + t];
                const unsigned rh = bf16_rne(xf);
                const float hif = __uint_as_float(rh << 16);
                const unsigned rl = bf16_rne(xf - hif);
                xbh[nt][s][j] = (short)rh;
                xbl[nt][s][j] = (short)rl;
            }
        }
    }

    float b1[4] = {-1e30f, -1e30f, -1e30f, -1e30f};
    float b2[4] = {-1e30f, -1e30f, -1e30f, -1e30f};
    int   bi[4] = {0, 0, 0, 0};

    const int kbase = khalf << 9;        // this wave's 512 codes

#define LOADT(S, KT) { \
    const int k0_ = kbase + ((KT) << 4); \
    const size_t ar_ = ((size_t)(k0_ + ln15) << 6) + lhi * 8; \
    ah0##S = *(const short8*)(ehib + ar_); \
    ah1##S = *(const short8*)(ehib + ar_ + 32); \
    al0##S = *(const short8*)(elob + ar_); \
    al1##S = *(const short8*)(elob + ar_ + 32); \
    snq##S = *(const f32x4*)(snh32 + k0_ + lhi * 4); \
}

#define COMPT(S, KT) { \
    const int k0_ = kbase + ((KT) << 4); \
    _Pragma("unroll") \
    for (int nt = 0; nt < 4; nt++) { \
        f32x4 acc = {0.f, 0.f, 0.f, 0.f}; \
        acc = __builtin_amdgcn_mfma_f32_16x16x32_bf16(ah0##S, xbh[nt][0], acc, 0, 0, 0); \
        acc = __builtin_amdgcn_mfma_f32_16x16x32_bf16(ah1##S, xbh[nt][1], acc, 0, 0, 0); \
        acc = __builtin_amdgcn_mfma_f32_16x16x32_bf16(ah0##S, xbl[nt][0], acc, 0, 0, 0); \
        acc = __builtin_amdgcn_mfma_f32_16x16x32_bf16(ah1##S, xbl[nt][1], acc, 0, 0, 0); \
        acc = __builtin_amdgcn_mfma_f32_16x16x32_bf16(al0##S, xbh[nt][0], acc, 0, 0, 0); \
        acc = __builtin_amdgcn_mfma_f32_16x16x32_bf16(al1##S, xbh[nt][1], acc, 0, 0, 0); \
        _Pragma("unroll") \
        for (int r = 0; r < 4; r++) { \
            const float m = acc[r] - snq##S[r]; \
            b2[nt] = fmaxf(b2[nt], fminf(b1[nt], m)); \
            if (m > b1[nt]) { b1[nt] = m; bi[nt] = k0_ + lhi * 4 + r; } \
        } \
    } \
}

    short8 ah0a, ah1a, al0a, al1a; f32x4 snqa;
    short8 ah0b, ah1b, al0b, al1b; f32x4 snqb;
    LOADT(a, 0)
    #pragma unroll 1
    for (int kt = 0; kt < 32; kt += 2) {
        LOADT(b, kt + 1)                  // prefetch odd tile
        COMPT(a, kt)                      // compute even tile
        LOADT(a, (kt + 2 < 32 ? kt + 2 : 31))   // prefetch next even (clamped)
        COMPT(b, kt + 1)                  // compute odd tile
    }
#undef LOADT
#undef COMPT

    // ---- merge top-2 across the 4 lane-groups holding each column ----
    #pragma unroll
    for (int nt = 0; nt < 4; nt++) {
        float B1 = b1[nt], B2 = b2[nt]; int I = bi[nt];
        #pragma unroll
        for (int off = 16; off <= 32; off <<= 1) {
            const float o1 = __shfl_xor(B1, off, 64);
            const float o2 = __shfl_xor(B2, off, 64);
            const int   oi = __shfl_xor(I,  off, 64);
            const float nb2 = fmaxf(fminf(B1, o1), fmaxf(B2, o2));
            if (o1 > B1 || (o1 == B1 && oi < I)) { B1 = o1; I = oi; }
            B2 = nb2;
        }
        // ---- cross-wave (k-split) partials through LDS ----
        if (khalf == 1 && lane < 16) {
            const int vloc = vgrp * 64 + nt * 16 + lane;
            red[vloc][0] = B1; red[vloc][1] = B2; red[vloc][2] = __int_as_float(I);
        }
        b1[nt] = B1; b2[nt] = B2; bi[nt] = I;
    }
    __syncthreads();

    if (khalf == 0) {
        #pragma unroll
        for (int nt = 0; nt < 4; nt++) {
            if (lane < 16) {
                const int vloc = vgrp * 64 + nt * 16 + lane;
                const float ob1 = red[vloc][0];
                const float ob2 = red[vloc][1];
                const int   oi  = __float_as_int(red[vloc][2]);
                float B1 = b1[nt], B2 = b2[nt]; int I = bi[nt];
                if (ob1 > B1) { B2 = fmaxf(B1, ob2); B1 = ob1; I = oi; }  // kh0 idx < kh1 idx
                else          { B2 = fmaxf(B2, ob1); }
                sidx[vloc] = (B1 - B2 <= SMARGIN) ? -1 : I;
            }
        }
    }
    __syncthreads();

    // ---- epilogue: thread = (vector vloc, dim half dh); NO fp32 atomics ----
    const int vloc = tid & 127;
    const int dh   = tid >> 7;           // 32-dim half
    const int t    = tblk + vloc;
    const int I    = sidx[vloc];
    const int v    = (b << 13) + t;

    if (I < 0) {
        if (dh == 0) { const int p = atomicAdd(flagcnt, 1); flagids[p] = v; }
    } else {
        if (dh == 0) idx32[v] = I;
        const float4* eq4 = (const float4*)(emb + I * DIM + dh * 32);
        float eqv[32];
        #pragma unroll
        for (int q = 0; q < 8; q++) {
            const float4 e4 = eq4[q];
            eqv[q * 4 + 0] = e4.x; eqv[q * 4 + 1] = e4.y;
            eqv[q * 4 + 2] = e4.z; eqv[q * 4 + 3] = e4.w;
        }
        #pragma unroll
        for (int j = 0; j < 32; j++) {
            const int d = dh * 32 + j;
            const float xf = xb[((size_t)d << 13) + t];
            out[((size_t)b << 19) + ((size_t)d << 13) + t] = xf + (eqv[j] - xf);
        }
    }
}

// ---------------- rescan: one block per flagged vector, exact fp64 ----------
__global__ __launch_bounds__(256) void vq_rescan(const float* __restrict__ x,
                                                 const float* __restrict__ emb,
                                                 const double* __restrict__ e64,
                                                 const double* __restrict__ snh64,
                                                 float* __restrict__ out,
                                                 int* __restrict__ idx32,
                                                 const int* __restrict__ flagcnt,
                                                 const int* __restrict__ flagids) {
    __shared__ double sb[256];
    __shared__ int    si[256];
    const int tid   = threadIdx.x;
    const int cslot = tid >> 2;          // 0..63 code slot (block-wide)
    const int dg    = tid & 3;           // 16-dim group
    const int count = *flagcnt;

    for (int i = blockIdx.x; i < count; i += gridDim.x) {
        const int v = flagids[i];
        const int b = v >> 13, t = v & (T_ - 1);
        const float* xb = x + ((size_t)b << 19) + t;

        double xd[16];
        #pragma unroll
        for (int j = 0; j < 16; j++) xd[j] = (double)xb[(size_t)(dg * 16 + j) << 13];

        double best = -1e300; int bi_ = 0;
        for (int cc = 0; cc < 16; cc++) {
            const int k = cc * 64 + cslot;
            const double* ek = e64 + (size_t)k * DIM + dg * 16;
            double a = 0.0;
            #pragma unroll
            for (int j = 0; j < 16; j++) a = __fma_rn(xd[j], ek[j], a);
            a += __shfl_xor(a, 1, 64);
            a += __shfl_xor(a, 2, 64);   // full dot across 4 dim-groups
            const double m = a - snh64[k];
            if (m > best) { best = m; bi_ = k; }  // ascending k: first-max kept
        }

        __syncthreads();                 // protect sb/si from previous iteration
        sb[tid] = best; si[tid] = bi_;
        __syncthreads();
        for (int s = 128; s > 0; s >>= 1) {
            if (tid < s) {
                const double ob = sb[tid + s]; const int oi = si[tid + s];
                if (ob > sb[tid] || (ob == sb[tid] && oi < si[tid])) {
                    sb[tid] = ob; si[tid] = oi;
                }
            }
            __syncthreads();
        }
        const int I = si[0];

        if (tid < 64) {                  // epilogue: thread = dim
            const float xf = xb[(size_t)tid << 13];
            out[((size_t)b << 19) + ((size_t)tid << 13) + t] = xf + (emb[I * DIM + tid] - xf);
            if (tid == 0) idx32[v] = I;
        }
    }
}

// ---- hist: per-block LDS histogram of idx32 -> global counts ----
__global__ __launch_bounds__(1024) void vq_hist(const int* __restrict__ idx32,
                                                int* __restrict__ counts) {
    __shared__ int h[K_CODES];
    const int tid = threadIdx.x;
    h[tid] = 0;
    __syncthreads();
    const int base = blockIdx.x * 2048 + tid;
    atomicAdd(&h[idx32[base]], 1);
    atomicAdd(&h[idx32[base + 1024]], 1);
    __syncthreads();
    const int c = h[tid];
    if (c) atomicAdd(&counts[tid], c);
}

// ---- scan: exclusive prefix sum of counts -> offsets, cursors ----
__global__ __launch_bounds__(1024) void vq_scan(const int* __restrict__ counts,
                                                int* __restrict__ offsets,
                                                int* __restrict__ cursors) {
    __shared__ int s[K_CODES];
    const int tid = threadIdx.x;
    const int c0 = counts[tid];
    int incl = c0;
    s[tid] = incl;
    __syncthreads();
    for (int off = 1; off < K_CODES; off <<= 1) {
        const int add = (tid >= off) ? s[tid - off] : 0;
        __syncthreads();
        incl += add;
        s[tid] = incl;
        __syncthreads();
    }
    const int excl = incl - c0;
    offsets[tid] = excl;
    cursors[tid] = excl;
}

// ---- scatter: counting-sort vector ids by code ----
__global__ __launch_bounds__(256) void vq_scatter(const int* __restrict__ idx32,
                                                  int* __restrict__ cursors,
                                                  int* __restrict__ order) {
    const int v = blockIdx.x * 256 + threadIdx.x;
    const int k = idx32[v];
    const int p = atomicAdd(&cursors[k], 1);
    order[p] = v;
}

// ---- reduce: block per code; sum assigned x, divide by cluster_size ----
__global__ __launch_bounds__(64) void vq_reduce(const float* __restrict__ x,
                                                const float* __restrict__ xT,
                                                const int* __restrict__ order,
                                                const int* __restrict__ offsets,
                                                const int* __restrict__ counts,
                                                float* __restrict__ newemb,
                                                int use_xt) {
    __shared__ int lv[2048];
    const int k = blockIdx.x;
    const int d = threadIdx.x;
    const int off = offsets[k];
    const int cnt = counts[k];
    float sum = 0.f;
    for (int base = 0; base < cnt; base += 2048) {
        const int m = min(2048, cnt - base);
        __syncthreads();
        for (int i = d; i < m; i += 64) lv[i] = order[off + base + i];
        __syncthreads();
        if (use_xt) {
            for (int i = 0; i < m; i++) sum += xT[(size_t)lv[i] * 64 + d];
        } else {
            for (int i = 0; i < m; i++) {
                const int v = lv[i];
                sum += x[((size_t)(v >> 13) << 19) + ((size_t)d << 13) + (v & (T_ - 1))];
            }
        }
    }
    const float c = (float)cnt;
    const float cluster = (c + EPSF) / (131072.0f + 1024.0f * EPSF) * 131072.0f;
    newemb[k * DIM + d] = sum / cluster;
}

extern "C" void kernel_launch(void* const* d_in, const int* in_sizes, int n_in,
                              void* d_out, int out_size, void* d_ws, size_t ws_size,
                              hipStream_t stream) {
    const float* x   = (const float*)d_in[0];
    const float* emb = (const float*)d_in[1];

    char* ws = (char*)d_ws;
    double*         e64     = (double*)(ws);                  //  524288 B
    double*         snh64   = (double*)(ws + 524288);         //    8192 B
    float*          snh32   = (float*)(ws + 532480);          //    4096 B
    unsigned short* ehib    = (unsigned short*)(ws + 536576); //  131072 B
    unsigned short* elob    = (unsigned short*)(ws + 667648); //  131072 B
    int*            idx32   = (int*)(ws + 798720);            //  524288 B
    int*            order   = (int*)(ws + 1323008);           //  524288 B
    int*            counts  = (int*)(ws + 1847296);           //    4096 B
    int*            flagcnt = (int*)(ws + 1851392);           //      64 B
    int*            offsets = (int*)(ws + 1851456);           //    4096 B
    int*            cursors = (int*)(ws + 1855552);           //    4096 B
    int*            flagids = (int*)(ws + 1859648);           //  524288 B
    float*          xT      = (float*)(ws + 2383936);         // 33554432 B (optional)
    const int use_xt = (ws_size >= (size_t)2383936 + 33554432) ? 1 : 0;

    float* out    = (float*)d_out;
    float* newemb = out + (size_t)B_ * DIM * T_;

    // zero counts + flagcnt (contiguous) every launch
    hipMemsetAsync(counts, 0, 4096 + 64, stream);

    vq_prep<<<K_CODES, 64, 0, stream>>>(emb, e64, snh64, snh32, ehib, elob);
    if (use_xt) vq_xt<<<2048, 256, 0, stream>>>(x, xT);
    vq_screen<<<N_ / 128, 256, 0, stream>>>(x, ehib, elob, snh32, emb, out, idx32,
                                            flagcnt, flagids);
    vq_rescan<<<1024, 256, 0, stream>>>(x, emb, e64, snh64, out, idx32,
                                        flagcnt, flagids);
    vq_hist<<<N_ / 2048, 1024, 0, stream>>>(idx32, counts);
    vq_scan<<<1, 1024, 0, stream>>>(counts, offsets, cursors);
    vq_scatter<<<N_ / 256, 256, 0, stream>>>(idx32, cursors, order);
    vq_reduce<<<K_CODES, 64, 0, stream>>>(x, xT, order, offsets, counts, newemb, use_xt);
}

// Round 11
// 204.744 us; speedup vs baseline: 1.3921x; 1.1193x over previous
//
#include <hip/hip_runtime.h>

#define K_CODES 1024
#define DIM 64
#define B_ 16
#define T_ 8192
#define N_ (B_*T_)          // 131072 vectors
#define EPSF 1e-5f
#define SMARGIN 5e-4f       // score-space margin >= 3x practical mfma error bound

typedef __attribute__((ext_vector_type(8))) short short8;   // 8 bf16 = 4 VGPR
typedef __attribute__((ext_vector_type(4))) float f32x4;

typedef __attribute__((address_space(1))) unsigned char g1_t;   // global
typedef __attribute__((address_space(3))) unsigned char l3_t;   // LDS

__device__ __forceinline__ unsigned bf16_rne(float f) {
    unsigned u = __float_as_uint(f);
    return (u + 0x7fffu + ((u >> 16) & 1u)) >> 16;
}

// ---- prep: e -> bf16 hi/lo tables, fp64 table, half-norms; zero accum ----
__global__ __launch_bounds__(64) void vq_prep(const float* __restrict__ emb,
                                              double* __restrict__ e64,
                                              double* __restrict__ snh64,
                                              float* __restrict__ snh32,
                                              unsigned short* __restrict__ ehib,
                                              unsigned short* __restrict__ elob,
                                              int* __restrict__ counts,
                                              int* __restrict__ flagcnt) {
    const int k = blockIdx.x;
    const int d = threadIdx.x;
    if (d == 0) counts[k] = 0;                    // replaces hipMemsetAsync
    if (k == 0 && d == 1) *flagcnt = 0;

    const float ef = emb[k * DIM + d];
    const unsigned rh = bf16_rne(ef);
    const float hif = __uint_as_float(rh << 16);
    const float lof = ef - hif;                   // exact (Sterbenz)
    const unsigned rl = bf16_rne(lof);
    ehib[k * DIM + d] = (unsigned short)rh;
    elob[k * DIM + d] = (unsigned short)rl;

    const double ed = (double)ef;
    e64[k * DIM + d] = ed;
    double s = ed * ed;
    #pragma unroll
    for (int off = 32; off; off >>= 1) s += __shfl_down(s, off, 64);
    if (d == 0) { snh64[k] = 0.5 * s; snh32[k] = (float)(0.5 * s); }
}

// ---- transpose x[b][d][t] -> xT[b*T+t][d] for the coalesced code-reduce ----
__global__ __launch_bounds__(256) void vq_xt(const float* __restrict__ x,
                                             float* __restrict__ xT) {
    __shared__ float tile[64][65];
    const int bb = blockIdx.x >> 7;           // batch
    const int t0 = (blockIdx.x & 127) << 6;   // 64-t tile
    const int tr = threadIdx.x & 63;
    const int dr = threadIdx.x >> 6;          // 4 rows per pass
    const float* xp = x + ((size_t)bb << 19) + t0;
    #pragma unroll
    for (int i = 0; i < 16; i++) {
        const int d = i * 4 + dr;
        tile[d][tr] = xp[((size_t)d << 13) + tr];
    }
    __syncthreads();
    float* op = xT + (((size_t)bb << 13) + t0) * 64;
    #pragma unroll
    for (int i = 0; i < 16; i++) {
        const int t = i * 4 + dr;
        op[(size_t)t * 64 + tr] = tile[tr][t];
    }
}

// ---- screen: split-bf16 MFMA, nt=4, async-LDS-staged e-tiles (dbuf+swz) ----
// block = 4 waves = 2 vgrp(64 vec) x 2 khalf(512 codes); 128 vec/block; grid 1024.
__global__ __launch_bounds__(256) void vq_screen(const float* __restrict__ x,
                                                 const unsigned short* __restrict__ ehib,
                                                 const unsigned short* __restrict__ elob,
                                                 const float* __restrict__ snh32,
                                                 const float* __restrict__ emb,
                                                 float* __restrict__ out,
                                                 int* __restrict__ idx32,
                                                 int* __restrict__ counts,
                                                 int* __restrict__ flagcnt,
                                                 int* __restrict__ flagids) {
    __shared__ unsigned short stg[2][2][2048]; // [khalf][buf][hi 1024hw | lo 1024hw]
    __shared__ float red[128][4];              // khalf=1 results: b1, b2, idx-bits
    __shared__ int sidx[128];                  // merged: code index, or -1 = flagged
    __shared__ int hcnt[K_CODES];              // per-block histogram

    const int tid   = threadIdx.x;
    const int wid   = tid >> 6;
    const int lane  = tid & 63;
    const int vgrp  = wid & 1;
    const int khalf = wid >> 1;
    const int ln15  = lane & 15;
    const int lhi   = lane >> 4;               // 0..3

    #pragma unroll
    for (int q = 0; q < 4; q++) hcnt[tid + q * 256] = 0;

    const int blk  = blockIdx.x;               // 1024 blocks x 128 vectors
    const int b    = blk >> 6;
    const int tblk = (blk & 63) << 7;
    const int t0   = tblk + vgrp * 64;
    const float* xb = x + ((size_t)b << 19);

    // ---- x B-fragments (hi/lo), register-resident ----
    short8 xbh[4][2], xbl[4][2];
    #pragma unroll
    for (int nt = 0; nt < 4; nt++) {
        const int t = t0 + nt * 16 + ln15;
        #pragma unroll
        for (int s = 0; s < 2; s++) {
            #pragma unroll
            for (int j = 0; j < 8; j++) {
                const int d = s * 32 + lhi * 8 + j;
                const float xf = xb[((size_t)d << 13) + t];
                const unsigned rh = bf16_rne(xf);
                const float hif = __uint_as_float(rh << 16);
                const unsigned rl = bf16_rne(xf - hif);
                xbh[nt][s][j] = (short)rh;
                xbl[nt][s][j] = (short)rl;
            }
        }
    }

    // staging: lane's pre-swizzled source byte offset within a 2KB half-tile.
    // LDS unit (row,c) must hold global unit (row, c^(row&7))  [G4 swizzle]
    const int srow = lane >> 3;                      // 0..7
    const int soff = (srow << 7) + (((lane & 7) ^ srow) << 4);
    // reader: swizzled halfword offsets (fixed per lane)
    const int rx = ln15 & 7;
    const int c0 = (lhi ^ rx) << 3;                  // hw offset of k-octet 0
    const int c1 = ((4 + lhi) ^ rx) << 3;            // hw offset of k-octet 4
    const int rbase = ln15 * 64;                     // hw: row stride 128 B

    const int kbase = khalf << 9;

#define STAGE(BUF, KT) { \
    const size_t tb_ = (size_t)(kbase + ((KT) << 4)) * DIM; \
    if (vgrp == 0) { \
        const unsigned char* g_ = (const unsigned char*)(ehib + tb_) + soff; \
        unsigned short* l_ = &stg[khalf][BUF][0]; \
        __builtin_amdgcn_global_load_lds((g1_t*)g_,          (l3_t*)l_,          16, 0, 0); \
        __builtin_amdgcn_global_load_lds((g1_t*)(g_ + 1024), (l3_t*)(l_ + 512),  16, 0, 0); \
    } else { \
        const unsigned char* g_ = (const unsigned char*)(elob + tb_) + soff; \
        unsigned short* l_ = &stg[khalf][BUF][1024]; \
        __builtin_amdgcn_global_load_lds((g1_t*)g_,          (l3_t*)l_,          16, 0, 0); \
        __builtin_amdgcn_global_load_lds((g1_t*)(g_ + 1024), (l3_t*)(l_ + 512),  16, 0, 0); \
    } \
}

    float b1[4] = {-1e30f, -1e30f, -1e30f, -1e30f};
    float b2[4] = {-1e30f, -1e30f, -1e30f, -1e30f};
    int   bi[4] = {0, 0, 0, 0};

#define BODY(BUF, KT, DOPRE, NKT) { \
    if (DOPRE) STAGE((BUF) ^ 1, NKT) \
    const unsigned short* lb = &stg[khalf][BUF][0]; \
    const short8 ah0 = *(const short8*)(lb + rbase + c0); \
    const short8 ah1 = *(const short8*)(lb + rbase + c1); \
    const short8 al0 = *(const short8*)(lb + 1024 + rbase + c0); \
    const short8 al1 = *(const short8*)(lb + 1024 + rbase + c1); \
    const int k0_ = kbase + ((KT) << 4); \
    const f32x4 snq = *(const f32x4*)(snh32 + k0_ + lhi * 4); \
    _Pragma("unroll") \
    for (int nt = 0; nt < 4; nt++) { \
        f32x4 acc = {0.f, 0.f, 0.f, 0.f}; \
        acc = __builtin_amdgcn_mfma_f32_16x16x32_bf16(ah0, xbh[nt][0], acc, 0, 0, 0); \
        acc = __builtin_amdgcn_mfma_f32_16x16x32_bf16(ah1, xbh[nt][1], acc, 0, 0, 0); \
        acc = __builtin_amdgcn_mfma_f32_16x16x32_bf16(ah0, xbl[nt][0], acc, 0, 0, 0); \
        acc = __builtin_amdgcn_mfma_f32_16x16x32_bf16(ah1, xbl[nt][1], acc, 0, 0, 0); \
        acc = __builtin_amdgcn_mfma_f32_16x16x32_bf16(al0, xbh[nt][0], acc, 0, 0, 0); \
        acc = __builtin_amdgcn_mfma_f32_16x16x32_bf16(al1, xbh[nt][1], acc, 0, 0, 0); \
        _Pragma("unroll") \
        for (int r = 0; r < 4; r++) { \
            const float m = acc[r] - snq[r]; \
            b2[nt] = fmaxf(b2[nt], fminf(b1[nt], m)); \
            if (m > b1[nt]) { b1[nt] = m; bi[nt] = k0_ + lhi * 4 + r; } \
        } \
    } \
    __syncthreads(); \
}

    STAGE(0, 0)
    __syncthreads();
    #pragma unroll 1
    for (int kt2 = 0; kt2 < 32; kt2 += 2) {
        BODY(0, kt2, 1, kt2 + 1)                       // compute buf0, stage buf1
        BODY(1, kt2 + 1, (kt2 < 30), kt2 + 2)          // compute buf1, stage buf0
    }
#undef STAGE
#undef BODY

    // ---- merge top-2 across the 4 lane-groups holding each column ----
    #pragma unroll
    for (int nt = 0; nt < 4; nt++) {
        float B1 = b1[nt], B2 = b2[nt]; int I = bi[nt];
        #pragma unroll
        for (int off = 16; off <= 32; off <<= 1) {
            const float o1 = __shfl_xor(B1, off, 64);
            const float o2 = __shfl_xor(B2, off, 64);
            const int   oi = __shfl_xor(I,  off, 64);
            const float nb2 = fmaxf(fminf(B1, o1), fmaxf(B2, o2));
            if (o1 > B1 || (o1 == B1 && oi < I)) { B1 = o1; I = oi; }
            B2 = nb2;
        }
        if (khalf == 1 && lane < 16) {
            const int vloc = vgrp * 64 + nt * 16 + lane;
            red[vloc][0] = B1; red[vloc][1] = B2; red[vloc][2] = __int_as_float(I);
        }
        b1[nt] = B1; b2[nt] = B2; bi[nt] = I;
    }
    __syncthreads();

    if (khalf == 0) {
        #pragma unroll
        for (int nt = 0; nt < 4; nt++) {
            if (lane < 16) {
                const int vloc = vgrp * 64 + nt * 16 + lane;
                const float ob1 = red[vloc][0];
                const float ob2 = red[vloc][1];
                const int   oi  = __float_as_int(red[vloc][2]);
                float B1 = b1[nt], B2 = b2[nt]; int I = bi[nt];
                if (ob1 > B1) { B2 = fmaxf(B1, ob2); B1 = ob1; I = oi; }  // kh0 idx < kh1 idx
                else          { B2 = fmaxf(B2, ob1); }
                sidx[vloc] = (B1 - B2 <= SMARGIN) ? -1 : I;
            }
        }
    }
    __syncthreads();

    // ---- epilogue: thread = (vector vloc, dim half dh); hist fused ----
    const int vloc = tid & 127;
    const int dh   = tid >> 7;           // 32-dim half
    const int t    = tblk + vloc;
    const int I    = sidx[vloc];
    const int v    = (b << 13) + t;

    if (I < 0) {
        if (dh == 0) { const int p = atomicAdd(flagcnt, 1); flagids[p] = v; }
    } else {
        if (dh == 0) { idx32[v] = I; atomicAdd(&hcnt[I], 1); }
        const float4* eq4 = (const float4*)(emb + I * DIM + dh * 32);
        float eqv[32];
        #pragma unroll
        for (int q = 0; q < 8; q++) {
            const float4 e4 = eq4[q];
            eqv[q * 4 + 0] = e4.x; eqv[q * 4 + 1] = e4.y;
            eqv[q * 4 + 2] = e4.z; eqv[q * 4 + 3] = e4.w;
        }
        #pragma unroll
        for (int j = 0; j < 32; j++) {
            const int d = dh * 32 + j;
            const float xf = xb[((size_t)d << 13) + t];
            out[((size_t)b << 19) + ((size_t)d << 13) + t] = xf + (eqv[j] - xf);
        }
    }
    __syncthreads();
    #pragma unroll
    for (int q = 0; q < 4; q++) {
        const int c = hcnt[tid + q * 256];
        if (c) atomicAdd(&counts[tid + q * 256], c);
    }
}

// ---------------- rescan: one block per flagged vector, exact fp64 ----------
__global__ __launch_bounds__(256) void vq_rescan(const float* __restrict__ x,
                                                 const float* __restrict__ emb,
                                                 const double* __restrict__ e64,
                                                 const double* __restrict__ snh64,
                                                 float* __restrict__ out,
                                                 int* __restrict__ idx32,
                                                 int* __restrict__ counts,
                                                 const int* __restrict__ flagcnt,
                                                 const int* __restrict__ flagids) {
    __shared__ double sb[256];
    __shared__ int    si[256];
    const int tid   = threadIdx.x;
    const int cslot = tid >> 2;          // 0..63 code slot (block-wide)
    const int dg    = tid & 3;           // 16-dim group
    const int count = *flagcnt;

    for (int i = blockIdx.x; i < count; i += gridDim.x) {
        const int v = flagids[i];
        const int b = v >> 13, t = v & (T_ - 1);
        const float* xb = x + ((size_t)b << 19) + t;

        double xd[16];
        #pragma unroll
        for (int j = 0; j < 16; j++) xd[j] = (double)xb[(size_t)(dg * 16 + j) << 13];

        double best = -1e300; int bi_ = 0;
        for (int cc = 0; cc < 16; cc++) {
            const int k = cc * 64 + cslot;
            const double* ek = e64 + (size_t)k * DIM + dg * 16;
            double a = 0.0;
            #pragma unroll
            for (int j = 0; j < 16; j++) a = __fma_rn(xd[j], ek[j], a);
            a += __shfl_xor(a, 1, 64);
            a += __shfl_xor(a, 2, 64);   // full dot across 4 dim-groups
            const double m = a - snh64[k];
            if (m > best) { best = m; bi_ = k; }  // ascending k: first-max kept
        }

        __syncthreads();                 // protect sb/si from previous iteration
        sb[tid] = best; si[tid] = bi_;
        __syncthreads();
        for (int s = 128; s > 0; s >>= 1) {
            if (tid < s) {
                const double ob = sb[tid + s]; const int oi = si[tid + s];
                if (ob > sb[tid] || (ob == sb[tid] && oi < si[tid])) {
                    sb[tid] = ob; si[tid] = oi;
                }
            }
            __syncthreads();
        }
        const int I = si[0];

        if (tid < 64) {                  // epilogue: thread = dim
            const float xf = xb[(size_t)tid << 13];
            out[((size_t)b << 19) + ((size_t)tid << 13) + t] = xf + (emb[I * DIM + tid] - xf);
            if (tid == 0) { idx32[v] = I; atomicAdd(&counts[I], 1); }
        }
    }
}

// ---- scan: exclusive prefix sum of counts -> offsets, cursors ----
__global__ __launch_bounds__(1024) void vq_scan(const int* __restrict__ counts,
                                                int* __restrict__ offsets,
                                                int* __restrict__ cursors) {
    __shared__ int s[K_CODES];
    const int tid = threadIdx.x;
    const int c0 = counts[tid];
    int incl = c0;
    s[tid] = incl;
    __syncthreads();
    for (int off = 1; off < K_CODES; off <<= 1) {
        const int add = (tid >= off) ? s[tid - off] : 0;
        __syncthreads();
        incl += add;
        s[tid] = incl;
        __syncthreads();
    }
    const int excl = incl - c0;
    offsets[tid] = excl;
    cursors[tid] = excl;
}

// ---- scatter: counting-sort vector ids by code ----
__global__ __launch_bounds__(256) void vq_scatter(const int* __restrict__ idx32,
                                                  int* __restrict__ cursors,
                                                  int* __restrict__ order) {
    const int v = blockIdx.x * 256 + threadIdx.x;
    const int k = idx32[v];
    const int p = atomicAdd(&cursors[k], 1);
    order[p] = v;
}

// ---- reduce: block per code; sum assigned x, divide by cluster_size ----
__global__ __launch_bounds__(64) void vq_reduce(const float* __restrict__ x,
                                                const float* __restrict__ xT,
                                                const int* __restrict__ order,
                                                const int* __restrict__ offsets,
                                                const int* __restrict__ counts,
                                                float* __restrict__ newemb,
                                                int use_xt) {
    __shared__ int lv[2048];
    const int k = blockIdx.x;
    const int d = threadIdx.x;
    const int off = offsets[k];
    const int cnt = counts[k];
    float sum = 0.f;
    for (int base = 0; base < cnt; base += 2048) {
        const int m = min(2048, cnt - base);
        __syncthreads();
        for (int i = d; i < m; i += 64) lv[i] = order[off + base + i];
        __syncthreads();
        if (use_xt) {
            for (int i = 0; i < m; i++) sum += xT[(size_t)lv[i] * 64 + d];
        } else {
            for (int i = 0; i < m; i++) {
                const int v = lv[i];
                sum += x[((size_t)(v >> 13) << 19) + ((size_t)d << 13) + (v & (T_ - 1))];
            }
        }
    }
    const float c = (float)cnt;
    const float cluster = (c + EPSF) / (131072.0f + 1024.0f * EPSF) * 131072.0f;
    newemb[k * DIM + d] = sum / cluster;
}

extern "C" void kernel_launch(void* const* d_in, const int* in_sizes, int n_in,
                              void* d_out, int out_size, void* d_ws, size_t ws_size,
                              hipStream_t stream) {
    const float* x   = (const float*)d_in[0];
    const float* emb = (const float*)d_in[1];

    char* ws = (char*)d_ws;
    double*         e64     = (double*)(ws);                  //  524288 B
    double*         snh64   = (double*)(ws + 524288);         //    8192 B
    float*          snh32   = (float*)(ws + 532480);          //    4096 B
    unsigned short* ehib    = (unsigned short*)(ws + 536576); //  131072 B
    unsigned short* elob    = (unsigned short*)(ws + 667648); //  131072 B
    int*            idx32   = (int*)(ws + 798720);            //  524288 B
    int*            order   = (int*)(ws + 1323008);           //  524288 B
    int*            counts  = (int*)(ws + 1847296);           //    4096 B
    int*            flagcnt = (int*)(ws + 1851392);           //      64 B
    int*            offsets = (int*)(ws + 1851456);           //    4096 B
    int*            cursors = (int*)(ws + 1855552);           //    4096 B
    int*            flagids = (int*)(ws + 1859648);           //  524288 B
    float*          xT      = (float*)(ws + 2383936);         // 33554432 B (optional)
    const int use_xt = (ws_size >= (size_t)2383936 + 33554432) ? 1 : 0;

    float* out    = (float*)d_out;
    float* newemb = out + (size_t)B_ * DIM * T_;

    vq_prep<<<K_CODES, 64, 0, stream>>>(emb, e64, snh64, snh32, ehib, elob,
                                        counts, flagcnt);
    if (use_xt) vq_xt<<<2048, 256, 0, stream>>>(x, xT);
    vq_screen<<<N_ / 128, 256, 0, stream>>>(x, ehib, elob, snh32, emb, out, idx32,
                                            counts, flagcnt, flagids);
    vq_rescan<<<1024, 256, 0, stream>>>(x, emb, e64, snh64, out, idx32, counts,
                                        flagcnt, flagids);
    vq_scan<<<1, 1024, 0, stream>>>(counts, offsets, cursors);
    vq_scatter<<<N_ / 256, 256, 0, stream>>>(idx32, cursors, order);
    vq_reduce<<<K_CODES, 64, 0, stream>>>(x, xT, order, offsets, counts, newemb, use_xt);
}